// Round 3
// baseline (479.372 us; speedup 1.0000x reference)
//
#include <hip/hip_runtime.h>

typedef __bf16 bf16_t;
typedef bf16_t bf16x8 __attribute__((ext_vector_type(8)));
typedef bf16_t bf16x4 __attribute__((ext_vector_type(4)));
typedef float f32x4 __attribute__((ext_vector_type(4)));

#define BATCH 4
#define SEQ 4096
#define EMBED 512
#define MTOT (BATCH * SEQ)
#define NSPLIT 2
#define KT (SEQ / NSPLIT)     // 2048 keys per block
#define BC 32
#define FITERS (KT / BC)      // 64

__device__ float  Lacc_g[MTOT];         // row sum-of-exp accumulator
__device__ bf16_t Wbf_g[EMBED * EMBED]; // W pre-converted to bf16

// async global->LDS, 16 B per lane; lds base must be wave-uniform
__device__ __forceinline__ void async_copy16(const bf16_t* g, bf16_t* l) {
    __builtin_amdgcn_global_load_lds(
        (const __attribute__((address_space(1))) unsigned int*)g,
        (__attribute__((address_space(3))) unsigned int*)l, 16, 0, 0);
}

// ---------------------------------------------------------------------------
// Stage 0a: W fp32 -> bf16 once; also zero Lacc_g.
// ---------------------------------------------------------------------------
__global__ __launch_bounds__(256) void cvt_w_kernel(const float* __restrict__ W) {
    const int i = (blockIdx.x * 256 + threadIdx.x) * 4;
    float4 v = *(const float4*)&W[i];
    bf16x4 o;
    o[0] = (bf16_t)v.x; o[1] = (bf16_t)v.y; o[2] = (bf16_t)v.z; o[3] = (bf16_t)v.w;
    *(bf16x4*)&Wbf_g[i] = o;
    if (blockIdx.x < 16)
        ((float4*)Lacc_g)[blockIdx.x * 256 + threadIdx.x] = make_float4(0.f, 0.f, 0.f, 0.f);
}

// ---------------------------------------------------------------------------
// Stage 0b: abuf = bf16(cos(x + theta)) — A operand precomputed once so the
// GEMM can DMA it (each A element is reused by 4 n-tiles; computing cos in
// the GEMM would re-read x 4x).
// ---------------------------------------------------------------------------
__global__ __launch_bounds__(256) void cvt_a_kernel(
    const float* __restrict__ x, const float* __restrict__ theta,
    bf16_t* __restrict__ abuf)
{
    const int i = (blockIdx.x * 256 + threadIdx.x) * 8;
    float4 a = *(const float4*)&x[i];
    float4 b = *(const float4*)&x[i + 4];
    const int e0 = i & 63;            // 8-aligned, no wrap within 8 elems
    bf16x8 o;
    o[0] = (bf16_t)__cosf(a.x + theta[e0 + 0]);
    o[1] = (bf16_t)__cosf(a.y + theta[e0 + 1]);
    o[2] = (bf16_t)__cosf(a.z + theta[e0 + 2]);
    o[3] = (bf16_t)__cosf(a.w + theta[e0 + 3]);
    o[4] = (bf16_t)__cosf(b.x + theta[e0 + 4]);
    o[5] = (bf16_t)__cosf(b.y + theta[e0 + 5]);
    o[6] = (bf16_t)__cosf(b.z + theta[e0 + 6]);
    o[7] = (bf16_t)__cosf(b.w + theta[e0 + 7]);
    *(bf16x8*)&abuf[i] = o;
}

// ---------------------------------------------------------------------------
// Stage 1: q = A @ W^T + b (M=16384, N=512, K=512), m97-style 128x128xBK64
// MFMA GEMM. 256 thr / 4 waves (2x2), 2 blocks/CU, LDS 32 KB, DMA staging
// (16B global_load_lds), 32 MFMA / wave / K-step, 8 K-steps.
// Epilogue writes kperm (MFMA-frag-major; layout identical to the R1 writer
// verified against flash) and qt (per-batch transpose), + bias.
// ---------------------------------------------------------------------------
__global__ __launch_bounds__(256, 2) void gemm_q_kernel(
    const bf16_t* __restrict__ abuf, const float* __restrict__ bias,
    bf16_t* __restrict__ kperm, bf16_t* __restrict__ qt)
{
    __shared__ alignas(16) bf16_t As[128 * 64];   // 16 KB, row-major [128][64]
    __shared__ alignas(16) bf16_t Bs[128 * 64];   // 16 KB

    const int t    = threadIdx.x;
    const int lane = t & 63;
    const int wave = t >> 6;
    const int l15  = lane & 15;
    const int quad = lane >> 4;
    const int m0   = (blockIdx.x >> 2) * 128;     // 128 m-tiles
    const int n0   = (blockIdx.x & 3) * 128;      // 4 n-tiles
    const int wm   = wave >> 1;                   // 0..1
    const int wn   = wave & 1;                    // 0..1

    const int drow = lane >> 3;                   // 0..7 (row within 8-row chunk)
    const int dseg = lane & 7;                    // 0..7 (16B segment)

    f32x4 acc[4][4];
#pragma unroll
    for (int mt = 0; mt < 4; ++mt)
#pragma unroll
        for (int nt = 0; nt < 4; ++nt) acc[mt][nt] = (f32x4){0.f, 0.f, 0.f, 0.f};

    for (int kk = 0; kk < 8; ++kk) {
        const int k0 = kk * 64;
        __syncthreads();     // previous compute done reading As/Bs
#pragma unroll
        for (int j = 0; j < 4; ++j) {
            const int c   = wave * 4 + j;         // chunk 0..15 = rows c*8..c*8+7
            const int row = c * 8 + drow;
            async_copy16(&abuf[(size_t)(m0 + row) * 512 + k0 + dseg * 8], &As[c * 512]);
            async_copy16(&Wbf_g[(size_t)(n0 + row) * 512 + k0 + dseg * 8], &Bs[c * 512]);
        }
        __syncthreads();     // vmcnt(0)-drained by compiler: DMA landed
#pragma unroll
        for (int kh = 0; kh < 2; ++kh) {
            bf16x8 af[4], bfr[4];
#pragma unroll
            for (int i = 0; i < 4; ++i) {
                af[i]  = *(const bf16x8*)&As[(wm * 64 + i * 16 + l15) * 64 + kh * 32 + quad * 8];
                bfr[i] = *(const bf16x8*)&Bs[(wn * 64 + i * 16 + l15) * 64 + kh * 32 + quad * 8];
            }
#pragma unroll
            for (int mt = 0; mt < 4; ++mt)
#pragma unroll
                for (int nt = 0; nt < 4; ++nt)
                    acc[mt][nt] = __builtin_amdgcn_mfma_f32_16x16x32_bf16(af[mt], bfr[nt], acc[mt][nt], 0, 0, 0);
        }
    }

    // epilogue: D row (m) = quad*4+r, D col (n) = l15
#pragma unroll
    for (int nt = 0; nt < 4; ++nt) {
        const int col = n0 + wn * 64 + nt * 16 + l15;
        const float bv = bias[col];
        const int kf = col >> 5;          // dim fragment
        const int qk = (col >> 3) & 3;    // quad-of-dim within 32
        const int jj = col & 7;
#pragma unroll
        for (int mt = 0; mt < 4; ++mt) {
            const int row0 = m0 + wm * 64 + mt * 16 + quad * 4;  // 4 consecutive rows
            const int b    = row0 >> 12;
            const int i0   = row0 & 4095;
            const int tile = i0 >> 5;
            const size_t kb = (size_t)b * (SEQ * EMBED) + (size_t)tile * 16384
                            + (size_t)(((i0 >> 4) & 1) * 16 + kf) * 512 + qk * 128
                            + (i0 & 15) * 8 + jj;
            bf16x4 pack;
#pragma unroll
            for (int r = 0; r < 4; ++r) {
                bf16_t qv = (bf16_t)(acc[mt][nt][r] + bv);
                kperm[kb + r * 8] = qv;
                pack[r] = qv;
            }
            *(bf16x4*)&qt[((size_t)(b * 512 + col) << 12) + i0] = pack;
        }
    }
}

// ---------------------------------------------------------------------------
// Stage 2: attention (R1 structure, frag-major LDS, atomic epilogue).
// Loop keeps R2's neutral tweaks: V loads before DMA, split QK chains,
// setprio around MFMA clusters.
// ---------------------------------------------------------------------------
__global__ __launch_bounds__(256, 2) void flash_kernel(
    const bf16_t* __restrict__ kp, const bf16_t* __restrict__ qt,
    float* __restrict__ out)
{
    __shared__ alignas(16) bf16_t Ks[2][32 * 512];   // 65536 B, frag-major
    __shared__ alignas(16) bf16_t Ps[2][4 * 512];    //  8192 B, frag-major

    const int t    = threadIdx.x;
    const int lane = t & 63;
    const int wave = t >> 6;
    const int l15  = lane & 15;
    const int quad = lane >> 4;

    // XCD-aware remap: 512 blocks, xcd = L&7 owns one (batch, ksplit) group
    const int L      = blockIdx.x;            // 0..511
    const int g      = L & 7;                 // 0..7
    const int qtile  = L >> 3;                // 0..63
    const int batch  = g >> 1;
    const int ksplit = g & 1;

    const int q0     = qtile * 64;
    const int kbase  = ksplit * KT;
    const int ktile0 = kbase >> 5;            // first 32-key tile index
    const bf16_t* kpb = kp + (size_t)batch * SEQ * EMBED;
    const bf16_t* qtb = qt + (size_t)batch * EMBED * SEQ;

    // stage K-tile 0: 32 frags x 1 KB, 8 per wave, linear DMA
#pragma unroll
    for (int cc = 0; cc < 8; ++cc) {
        const int f = cc * 4 + wave;
        async_copy16(&kpb[(size_t)ktile0 * 16384 + f * 512 + lane * 8],
                     &Ks[0][f * 512]);
    }

    // Q B-frags (wave owns q-rows q0+wave*16..+15), read from frag-major kperm
    bf16x8 bQ[16];
    {
        const size_t qb = (size_t)(qtile * 2 + (wave >> 1)) * 16384
                        + (size_t)(wave & 1) * 16 * 512;
#pragma unroll
        for (int kf = 0; kf < 16; ++kf)
            bQ[kf] = *(const bf16x8*)&kpb[qb + kf * 512 + quad * 128 + l15 * 8];
    }

    f32x4 O[4][8];   // PV e-split: wave owns e-range wave*128 (8 n-tiles x 16)
#pragma unroll
    for (int m = 0; m < 4; ++m)
#pragma unroll
        for (int n = 0; n < 8; ++n) O[m][n] = (f32x4){0.f, 0.f, 0.f, 0.f};
    float lpart = 0.f;

    for (int it = 0; it < FITERS; ++it) {
        const int cbuf = it & 1;
        const int pbuf = cbuf ^ 1;
        __syncthreads();   // DMA K(it) landed; Ps(it-1) visible; Ks[pbuf] reads done
        // ---- V(it-1) global loads FIRST (older in vmcnt queue than DMA) ----
        bf16x8 bv[8];
        if (it) {
            const int kv = kbase + (it - 1) * BC;
#pragma unroll
            for (int n = 0; n < 8; ++n)
                bv[n] = *(const bf16x8*)&qtb[(size_t)(wave * 128 + n * 16 + l15) * 4096
                                             + kv + quad * 8];
        }
        // ---- issue DMA K(it+1) into Ks[pbuf] (stays in flight past PV) ----
        if (it + 1 < FITERS) {
#pragma unroll
            for (int cc = 0; cc < 8; ++cc) {
                const int f = cc * 4 + wave;
                async_copy16(&kpb[(size_t)(ktile0 + it + 1) * 16384 + f * 512 + lane * 8],
                             &Ks[pbuf][f * 512]);
            }
        }
        // ---- QK(it): S^T = K * Q^T, A=K frag (seq. lane*16 read), B=Q regs ----
        f32x4 s[2];
        __builtin_amdgcn_s_setprio(1);
#pragma unroll
        for (int kt = 0; kt < 2; ++kt) {
            f32x4 a0 = (f32x4){0.f, 0.f, 0.f, 0.f};
            f32x4 a1 = (f32x4){0.f, 0.f, 0.f, 0.f};
#pragma unroll
            for (int kf = 0; kf < 8; ++kf) {
                bf16x8 ak0 = *(const bf16x8*)&Ks[cbuf][(kt * 16 + kf) * 512 + lane * 8];
                bf16x8 ak1 = *(const bf16x8*)&Ks[cbuf][(kt * 16 + 8 + kf) * 512 + lane * 8];
                a0 = __builtin_amdgcn_mfma_f32_16x16x32_bf16(ak0, bQ[kf],     a0, 0, 0, 0);
                a1 = __builtin_amdgcn_mfma_f32_16x16x32_bf16(ak1, bQ[8 + kf], a1, 0, 0, 0);
            }
            s[kt] = a0 + a1;
        }
        __builtin_amdgcn_s_setprio(0);
        // ---- P = exp(s/8): lane holds P[q=wave*16+l15][key=kt*16+quad*4+r] ----
#pragma unroll
        for (int kt = 0; kt < 2; ++kt) {
            bf16x4 pk;
#pragma unroll
            for (int r = 0; r < 4; ++r) {
                bf16_t pb = (bf16_t)__expf(s[kt][r] * 0.125f);
                lpart += (float)pb;
                pk[r] = pb;
            }
            *(bf16x4*)&Ps[cbuf][wave * 512 + (kt * 2 + (quad >> 1)) * 128
                                + l15 * 8 + (quad & 1) * 4] = pk;
        }
        // ---- PV(it-1): A=P frags (seq. lane*16 read), B=bv ----
        if (it) {
            bf16x8 pa[4];
#pragma unroll
            for (int mt = 0; mt < 4; ++mt)
                pa[mt] = *(const bf16x8*)&Ps[pbuf][mt * 512 + lane * 8];
            __builtin_amdgcn_s_setprio(1);
#pragma unroll
            for (int n = 0; n < 8; ++n)
#pragma unroll
                for (int mt = 0; mt < 4; ++mt)
                    O[mt][n] = __builtin_amdgcn_mfma_f32_16x16x32_bf16(pa[mt], bv[n], O[mt][n], 0, 0, 0);
            __builtin_amdgcn_s_setprio(0);
        }
    }
    // ---- final PV(FITERS-1) ----
    __syncthreads();
    {
        const int pbuf = (FITERS - 1) & 1;
        const int kv = kbase + (FITERS - 1) * BC;
        bf16x8 bv[8];
#pragma unroll
        for (int n = 0; n < 8; ++n)
            bv[n] = *(const bf16x8*)&qtb[(size_t)(wave * 128 + n * 16 + l15) * 4096
                                         + kv + quad * 8];
        bf16x8 pa[4];
#pragma unroll
        for (int mt = 0; mt < 4; ++mt)
            pa[mt] = *(const bf16x8*)&Ps[pbuf][mt * 512 + lane * 8];
        __builtin_amdgcn_s_setprio(1);
#pragma unroll
        for (int n = 0; n < 8; ++n)
#pragma unroll
            for (int mt = 0; mt < 4; ++mt)
                O[mt][n] = __builtin_amdgcn_mfma_f32_16x16x32_bf16(pa[mt], bv[n], O[mt][n], 0, 0, 0);
        __builtin_amdgcn_s_setprio(0);
    }

    // ---- row exp-sums: row = wave*16+l15, keys spread over quad ----
    {
        float ls = lpart;
        ls += __shfl_xor(ls, 16);
        ls += __shfl_xor(ls, 32);
        if (quad == 0)
            atomicAdd(&Lacc_g[batch * SEQ + q0 + wave * 16 + l15], ls);
    }
    // ---- unnormalized O -> out; D: row=quad*4+r (q-row), col=l15 (e) ----
#pragma unroll
    for (int mt = 0; mt < 4; ++mt)
#pragma unroll
        for (int r = 0; r < 4; ++r) {
            const size_t row = (size_t)batch * SEQ + q0 + mt * 16 + quad * 4 + r;
#pragma unroll
            for (int n = 0; n < 8; ++n)
                atomicAdd(&out[row * 512 + wave * 128 + n * 16 + l15], O[mt][n][r]);
        }
}

// out[row][e] /= Lacc_g[row]
__global__ __launch_bounds__(256) void norm_kernel(float* __restrict__ out)
{
    const int idx = blockIdx.x * 256 + threadIdx.x;   // float4 index
    float4 v = ((float4*)out)[idx];
    const float inv = 1.0f / Lacc_g[idx >> 7];
    v.x *= inv; v.y *= inv; v.z *= inv; v.w *= inv;
    ((float4*)out)[idx] = v;
}

extern "C" void kernel_launch(void* const* d_in, const int* in_sizes, int n_in,
                              void* d_out, int out_size, void* d_ws, size_t ws_size,
                              hipStream_t stream) {
    const float* x     = (const float*)d_in[0];
    const float* theta = (const float*)d_in[1];
    const float* W     = (const float*)d_in[2];
    const float* bias  = (const float*)d_in[3];
    float* out    = (float*)d_out;
    bf16_t* kperm = (bf16_t*)d_ws;                      // [4][128 tiles][32 frags][512] bf16
    bf16_t* qt    = kperm + (size_t)MTOT * EMBED;       // [4][512][4096] bf16
    bf16_t* abuf  = qt + (size_t)MTOT * EMBED;          // [16384][512] bf16

    hipMemsetAsync(out, 0, (size_t)MTOT * EMBED * sizeof(float), stream);

    cvt_w_kernel<<<dim3(EMBED * EMBED / 4 / 256), dim3(256), 0, stream>>>(W);

    cvt_a_kernel<<<dim3(MTOT * EMBED / 8 / 256), dim3(256), 0, stream>>>(x, theta, abuf);

    gemm_q_kernel<<<dim3((MTOT / 128) * 4), dim3(256), 0, stream>>>(abuf, bias, kperm, qt);

    flash_kernel<<<dim3(64 * BATCH * NSPLIT), dim3(256), 0, stream>>>(kperm, qt, out);

    norm_kernel<<<dim3(MTOT * EMBED / 4 / 256), dim3(256), 0, stream>>>(out);
}

// Round 4
// 378.655 us; speedup vs baseline: 1.2660x; 1.2660x over previous
//
#include <hip/hip_runtime.h>

typedef __bf16 bf16_t;
typedef bf16_t bf16x8 __attribute__((ext_vector_type(8)));
typedef bf16_t bf16x4 __attribute__((ext_vector_type(4)));
typedef float f32x4 __attribute__((ext_vector_type(4)));

#define BATCH 4
#define SEQ 4096
#define EMBED 512
#define MTOT (BATCH * SEQ)
#define NSPLIT 2
#define KT (SEQ / NSPLIT)     // 2048 keys per block
#define BC 32
#define FITERS (KT / BC)      // 64

__device__ float  Lacc_g[MTOT];         // row sum-of-exp accumulator
__device__ bf16_t Wbf_g[EMBED * EMBED]; // W pre-converted to bf16

// async global->LDS, 16 B per lane; lds base must be wave-uniform
__device__ __forceinline__ void async_copy16(const bf16_t* g, bf16_t* l) {
    __builtin_amdgcn_global_load_lds(
        (const __attribute__((address_space(1))) unsigned int*)g,
        (__attribute__((address_space(3))) unsigned int*)l, 16, 0, 0);
}

// ---------------------------------------------------------------------------
// Stage 0a: W fp32 -> bf16 once; also zero Lacc_g.
// ---------------------------------------------------------------------------
__global__ __launch_bounds__(256) void cvt_w_kernel(const float* __restrict__ W) {
    const int i = (blockIdx.x * 256 + threadIdx.x) * 4;
    float4 v = *(const float4*)&W[i];
    bf16x4 o;
    o[0] = (bf16_t)v.x; o[1] = (bf16_t)v.y; o[2] = (bf16_t)v.z; o[3] = (bf16_t)v.w;
    *(bf16x4*)&Wbf_g[i] = o;
    if (blockIdx.x < 16)
        ((float4*)Lacc_g)[blockIdx.x * 256 + threadIdx.x] = make_float4(0.f, 0.f, 0.f, 0.f);
}

// ---------------------------------------------------------------------------
// Stage 0b: abuf = bf16(cos(x + theta)) — A operand precomputed once.
// ---------------------------------------------------------------------------
__global__ __launch_bounds__(256) void cvt_a_kernel(
    const float* __restrict__ x, const float* __restrict__ theta,
    bf16_t* __restrict__ abuf)
{
    const int i = (blockIdx.x * 256 + threadIdx.x) * 8;
    float4 a = *(const float4*)&x[i];
    float4 b = *(const float4*)&x[i + 4];
    const int e0 = i & 63;            // 8-aligned, no wrap within 8 elems
    bf16x8 o;
    o[0] = (bf16_t)__cosf(a.x + theta[e0 + 0]);
    o[1] = (bf16_t)__cosf(a.y + theta[e0 + 1]);
    o[2] = (bf16_t)__cosf(a.z + theta[e0 + 2]);
    o[3] = (bf16_t)__cosf(a.w + theta[e0 + 3]);
    o[4] = (bf16_t)__cosf(b.x + theta[e0 + 4]);
    o[5] = (bf16_t)__cosf(b.y + theta[e0 + 5]);
    o[6] = (bf16_t)__cosf(b.z + theta[e0 + 6]);
    o[7] = (bf16_t)__cosf(b.w + theta[e0 + 7]);
    *(bf16x8*)&abuf[i] = o;
}

// ---------------------------------------------------------------------------
// Stage 1: q = A @ W^T + b (M=16384, N=512, K=512), 128x128xBK64 MFMA GEMM.
// 256 thr / 4 waves (2x2), 2 blocks/CU, LDS 32 KB, DMA staging.
// T2 both-sides swizzle (rule #21): DMA source segment pre-swizzled
// (dseg ^ drow) so LDS[row][seg] = global[row][seg ^ (row&7)]; ds_read
// applies the same XOR. Takes LDS reads from 16 hits/bank/quarter to the
// 2-hit minimum (16-way conflict -> free).
// Epilogue writes kperm (MFMA-frag-major, layout verified vs flash) + qt.
// ---------------------------------------------------------------------------
__global__ __launch_bounds__(256, 2) void gemm_q_kernel(
    const bf16_t* __restrict__ abuf, const float* __restrict__ bias,
    bf16_t* __restrict__ kperm, bf16_t* __restrict__ qt)
{
    __shared__ alignas(16) bf16_t As[128 * 64];   // 16 KB, [128 rows][8 segs of 16B]
    __shared__ alignas(16) bf16_t Bs[128 * 64];   // 16 KB

    const int t    = threadIdx.x;
    const int lane = t & 63;
    const int wave = t >> 6;
    const int l15  = lane & 15;
    const int quad = lane >> 4;
    const int m0   = (blockIdx.x >> 2) * 128;     // 128 m-tiles
    const int n0   = (blockIdx.x & 3) * 128;      // 4 n-tiles
    const int wm   = wave >> 1;                   // 0..1
    const int wn   = wave & 1;                    // 0..1

    const int drow = lane >> 3;                   // 0..7 (row within 8-row chunk)
    const int dseg = lane & 7;                    // 0..7 (16B segment)
    const int sseg = dseg ^ drow;                 // pre-swizzled source segment

    f32x4 acc[4][4];
#pragma unroll
    for (int mt = 0; mt < 4; ++mt)
#pragma unroll
        for (int nt = 0; nt < 4; ++nt) acc[mt][nt] = (f32x4){0.f, 0.f, 0.f, 0.f};

    for (int kk = 0; kk < 8; ++kk) {
        const int k0 = kk * 64;
        __syncthreads();     // previous compute done reading As/Bs
#pragma unroll
        for (int j = 0; j < 4; ++j) {
            const int c   = wave * 4 + j;         // chunk 0..15 = rows c*8..c*8+7
            const int row = c * 8 + drow;
            async_copy16(&abuf[(size_t)(m0 + row) * 512 + k0 + sseg * 8], &As[c * 512]);
            async_copy16(&Wbf_g[(size_t)(n0 + row) * 512 + k0 + sseg * 8], &Bs[c * 512]);
        }
        __syncthreads();     // DMA landed
#pragma unroll
        for (int kh = 0; kh < 2; ++kh) {
            bf16x8 af[4], bfr[4];
#pragma unroll
            for (int i = 0; i < 4; ++i) {
                const int rA = wm * 64 + i * 16 + l15;
                const int rB = wn * 64 + i * 16 + l15;
                const int sg = kh * 4 + quad;
                af[i]  = *(const bf16x8*)&As[rA * 64 + (sg ^ (rA & 7)) * 8];
                bfr[i] = *(const bf16x8*)&Bs[rB * 64 + (sg ^ (rB & 7)) * 8];
            }
#pragma unroll
            for (int mt = 0; mt < 4; ++mt)
#pragma unroll
                for (int nt = 0; nt < 4; ++nt)
                    acc[mt][nt] = __builtin_amdgcn_mfma_f32_16x16x32_bf16(af[mt], bfr[nt], acc[mt][nt], 0, 0, 0);
        }
    }

    // epilogue: D row (m) = quad*4+r, D col (n) = l15
#pragma unroll
    for (int nt = 0; nt < 4; ++nt) {
        const int col = n0 + wn * 64 + nt * 16 + l15;
        const float bv = bias[col];
        const int kf = col >> 5;          // dim fragment
        const int qk = (col >> 3) & 3;    // quad-of-dim within 32
        const int jj = col & 7;
#pragma unroll
        for (int mt = 0; mt < 4; ++mt) {
            const int row0 = m0 + wm * 64 + mt * 16 + quad * 4;  // 4 consecutive rows
            const int b    = row0 >> 12;
            const int i0   = row0 & 4095;
            const int tile = i0 >> 5;
            const size_t kb = (size_t)b * (SEQ * EMBED) + (size_t)tile * 16384
                            + (size_t)(((i0 >> 4) & 1) * 16 + kf) * 512 + qk * 128
                            + (i0 & 15) * 8 + jj;
            bf16x4 pack;
#pragma unroll
            for (int r = 0; r < 4; ++r) {
                bf16_t qv = (bf16_t)(acc[mt][nt][r] + bv);
                kperm[kb + r * 8] = qv;
                pack[r] = qv;
            }
            *(bf16x4*)&qt[((size_t)(b * 512 + col) << 12) + i0] = pack;
        }
    }
}

// ---------------------------------------------------------------------------
// Stage 2: attention — EXACT R1 loop (275 us / 66 MB W / 27 MB F proven).
// R2's reorder + chain-split + setprio caused scratch spills (+183 MB HBM
// writes) at the 256-reg cliff; reverted.
// ---------------------------------------------------------------------------
__global__ __launch_bounds__(256, 2) void flash_kernel(
    const bf16_t* __restrict__ kp, const bf16_t* __restrict__ qt,
    float* __restrict__ out)
{
    __shared__ alignas(16) bf16_t Ks[2][32 * 512];   // 65536 B, frag-major
    __shared__ alignas(16) bf16_t Ps[2][4 * 512];    //  8192 B, frag-major

    const int t    = threadIdx.x;
    const int lane = t & 63;
    const int wave = t >> 6;
    const int l15  = lane & 15;
    const int quad = lane >> 4;

    // XCD-aware remap: 512 blocks, xcd = L&7 owns one (batch, ksplit) group
    const int L      = blockIdx.x;            // 0..511
    const int g      = L & 7;                 // 0..7
    const int qtile  = L >> 3;                // 0..63
    const int batch  = g >> 1;
    const int ksplit = g & 1;

    const int q0     = qtile * 64;
    const int kbase  = ksplit * KT;
    const int ktile0 = kbase >> 5;            // first 32-key tile index
    const bf16_t* kpb = kp + (size_t)batch * SEQ * EMBED;
    const bf16_t* qtb = qt + (size_t)batch * EMBED * SEQ;

    // stage K-tile 0: 32 frags x 1 KB, 8 per wave, linear DMA
#pragma unroll
    for (int cc = 0; cc < 8; ++cc) {
        const int f = cc * 4 + wave;
        async_copy16(&kpb[(size_t)ktile0 * 16384 + f * 512 + lane * 8],
                     &Ks[0][f * 512]);
    }

    // Q B-frags (wave owns q-rows q0+wave*16..+15), read from frag-major kperm
    bf16x8 bQ[16];
    {
        const size_t qb = (size_t)(qtile * 2 + (wave >> 1)) * 16384
                        + (size_t)(wave & 1) * 16 * 512;
#pragma unroll
        for (int kf = 0; kf < 16; ++kf)
            bQ[kf] = *(const bf16x8*)&kpb[qb + kf * 512 + quad * 128 + l15 * 8];
    }

    f32x4 O[4][8];   // PV e-split: wave owns e-range wave*128 (8 n-tiles x 16)
#pragma unroll
    for (int m = 0; m < 4; ++m)
#pragma unroll
        for (int n = 0; n < 8; ++n) O[m][n] = (f32x4){0.f, 0.f, 0.f, 0.f};
    float lpart = 0.f;

    for (int it = 0; it < FITERS; ++it) {
        const int cbuf = it & 1;
        const int pbuf = cbuf ^ 1;
        __syncthreads();   // DMA K(it) landed; Ps(it-1) visible; Ks[pbuf] reads done
        // ---- issue DMA K(it+1) into Ks[pbuf] (waited at next barrier) ----
        if (it + 1 < FITERS) {
#pragma unroll
            for (int cc = 0; cc < 8; ++cc) {
                const int f = cc * 4 + wave;
                async_copy16(&kpb[(size_t)(ktile0 + it + 1) * 16384 + f * 512 + lane * 8],
                             &Ks[pbuf][f * 512]);
            }
        }
        // ---- V(it-1) global loads (latency hidden behind QK below) ----
        bf16x8 bv[8];
        if (it) {
            const int kv = kbase + (it - 1) * BC;
#pragma unroll
            for (int n = 0; n < 8; ++n)
                bv[n] = *(const bf16x8*)&qtb[(size_t)(wave * 128 + n * 16 + l15) * 4096
                                             + kv + quad * 8];
        }
        // ---- QK(it): S^T = K * Q^T, A=K frag (seq. lane*16 read), B=Q regs ----
        f32x4 s[2];
#pragma unroll
        for (int kt = 0; kt < 2; ++kt) {
            f32x4 a = (f32x4){0.f, 0.f, 0.f, 0.f};
#pragma unroll
            for (int kf = 0; kf < 16; ++kf) {
                bf16x8 ak = *(const bf16x8*)&Ks[cbuf][(kt * 16 + kf) * 512 + lane * 8];
                a = __builtin_amdgcn_mfma_f32_16x16x32_bf16(ak, bQ[kf], a, 0, 0, 0);
            }
            s[kt] = a;
        }
        // ---- P = exp(s/8): lane holds P[q=wave*16+l15][key=kt*16+quad*4+r] ----
#pragma unroll
        for (int kt = 0; kt < 2; ++kt) {
            bf16x4 pk;
#pragma unroll
            for (int r = 0; r < 4; ++r) {
                bf16_t pb = (bf16_t)__expf(s[kt][r] * 0.125f);
                lpart += (float)pb;
                pk[r] = pb;
            }
            *(bf16x4*)&Ps[cbuf][wave * 512 + (kt * 2 + (quad >> 1)) * 128
                                + l15 * 8 + (quad & 1) * 4] = pk;
        }
        // ---- PV(it-1): A=P frags (seq. lane*16 read), B=bv ----
        if (it) {
            bf16x8 pa[4];
#pragma unroll
            for (int mt = 0; mt < 4; ++mt)
                pa[mt] = *(const bf16x8*)&Ps[pbuf][mt * 512 + lane * 8];
#pragma unroll
            for (int n = 0; n < 8; ++n)
#pragma unroll
                for (int mt = 0; mt < 4; ++mt)
                    O[mt][n] = __builtin_amdgcn_mfma_f32_16x16x32_bf16(pa[mt], bv[n], O[mt][n], 0, 0, 0);
        }
    }
    // ---- final PV(FITERS-1) ----
    __syncthreads();
    {
        const int pbuf = (FITERS - 1) & 1;
        const int kv = kbase + (FITERS - 1) * BC;
        bf16x8 bv[8];
#pragma unroll
        for (int n = 0; n < 8; ++n)
            bv[n] = *(const bf16x8*)&qtb[(size_t)(wave * 128 + n * 16 + l15) * 4096
                                         + kv + quad * 8];
        bf16x8 pa[4];
#pragma unroll
        for (int mt = 0; mt < 4; ++mt)
            pa[mt] = *(const bf16x8*)&Ps[pbuf][mt * 512 + lane * 8];
#pragma unroll
        for (int n = 0; n < 8; ++n)
#pragma unroll
            for (int mt = 0; mt < 4; ++mt)
                O[mt][n] = __builtin_amdgcn_mfma_f32_16x16x32_bf16(pa[mt], bv[n], O[mt][n], 0, 0, 0);
    }

    // ---- row exp-sums: row = wave*16+l15, keys spread over quad ----
    {
        float ls = lpart;
        ls += __shfl_xor(ls, 16);
        ls += __shfl_xor(ls, 32);
        if (quad == 0)
            atomicAdd(&Lacc_g[batch * SEQ + q0 + wave * 16 + l15], ls);
    }
    // ---- unnormalized O -> out; D: row=quad*4+r (q-row), col=l15 (e) ----
#pragma unroll
    for (int mt = 0; mt < 4; ++mt)
#pragma unroll
        for (int r = 0; r < 4; ++r) {
            const size_t row = (size_t)batch * SEQ + q0 + mt * 16 + quad * 4 + r;
#pragma unroll
            for (int n = 0; n < 8; ++n)
                atomicAdd(&out[row * 512 + wave * 128 + n * 16 + l15], O[mt][n][r]);
        }
}

// out[row][e] /= Lacc_g[row]
__global__ __launch_bounds__(256) void norm_kernel(float* __restrict__ out)
{
    const int idx = blockIdx.x * 256 + threadIdx.x;   // float4 index
    float4 v = ((float4*)out)[idx];
    const float inv = 1.0f / Lacc_g[idx >> 7];
    v.x *= inv; v.y *= inv; v.z *= inv; v.w *= inv;
    ((float4*)out)[idx] = v;
}

extern "C" void kernel_launch(void* const* d_in, const int* in_sizes, int n_in,
                              void* d_out, int out_size, void* d_ws, size_t ws_size,
                              hipStream_t stream) {
    const float* x     = (const float*)d_in[0];
    const float* theta = (const float*)d_in[1];
    const float* W     = (const float*)d_in[2];
    const float* bias  = (const float*)d_in[3];
    float* out    = (float*)d_out;
    bf16_t* kperm = (bf16_t*)d_ws;                      // [4][128 tiles][32 frags][512] bf16
    bf16_t* qt    = kperm + (size_t)MTOT * EMBED;       // [4][512][4096] bf16
    bf16_t* abuf  = qt + (size_t)MTOT * EMBED;          // [16384][512] bf16

    hipMemsetAsync(out, 0, (size_t)MTOT * EMBED * sizeof(float), stream);

    cvt_w_kernel<<<dim3(EMBED * EMBED / 4 / 256), dim3(256), 0, stream>>>(W);

    cvt_a_kernel<<<dim3(MTOT * EMBED / 8 / 256), dim3(256), 0, stream>>>(x, theta, abuf);

    gemm_q_kernel<<<dim3((MTOT / 128) * 4), dim3(256), 0, stream>>>(abuf, bias, kperm, qt);

    flash_kernel<<<dim3(64 * BATCH * NSPLIT), dim3(256), 0, stream>>>(kperm, qt, out);

    norm_kernel<<<dim3(MTOT * EMBED / 4 / 256), dim3(256), 0, stream>>>(out);
}

// Round 5
// 366.143 us; speedup vs baseline: 1.3092x; 1.0342x over previous
//
#include <hip/hip_runtime.h>

typedef __bf16 bf16_t;
typedef bf16_t bf16x8 __attribute__((ext_vector_type(8)));
typedef bf16_t bf16x4 __attribute__((ext_vector_type(4)));
typedef float f32x4 __attribute__((ext_vector_type(4)));

#define BATCH 4
#define SEQ 4096
#define EMBED 512
#define MTOT (BATCH * SEQ)
#define NSPLIT 2
#define KT (SEQ / NSPLIT)     // 2048 keys per block
#define BC 32
#define FITERS (KT / BC)      // 64

__device__ float  Lacc_g[MTOT];         // row sum-of-exp accumulator
__device__ bf16_t Wbf_g[EMBED * EMBED]; // W pre-converted to bf16

// async global->LDS, 16 B per lane; lds base must be wave-uniform
__device__ __forceinline__ void async_copy16(const bf16_t* g, bf16_t* l) {
    __builtin_amdgcn_global_load_lds(
        (const __attribute__((address_space(1))) unsigned int*)g,
        (__attribute__((address_space(3))) unsigned int*)l, 16, 0, 0);
}

// ---------------------------------------------------------------------------
// Stage 0a: W fp32 -> bf16 once; also zero Lacc_g.
// ---------------------------------------------------------------------------
__global__ __launch_bounds__(256) void cvt_w_kernel(const float* __restrict__ W) {
    const int i = (blockIdx.x * 256 + threadIdx.x) * 4;
    float4 v = *(const float4*)&W[i];
    bf16x4 o;
    o[0] = (bf16_t)v.x; o[1] = (bf16_t)v.y; o[2] = (bf16_t)v.z; o[3] = (bf16_t)v.w;
    *(bf16x4*)&Wbf_g[i] = o;
    if (blockIdx.x < 16)
        ((float4*)Lacc_g)[blockIdx.x * 256 + threadIdx.x] = make_float4(0.f, 0.f, 0.f, 0.f);
}

// ---------------------------------------------------------------------------
// Stage 0b: abuf = bf16(cos(x + theta)) — A operand precomputed once.
// ---------------------------------------------------------------------------
__global__ __launch_bounds__(256) void cvt_a_kernel(
    const float* __restrict__ x, const float* __restrict__ theta,
    bf16_t* __restrict__ abuf)
{
    const int i = (blockIdx.x * 256 + threadIdx.x) * 8;
    float4 a = *(const float4*)&x[i];
    float4 b = *(const float4*)&x[i + 4];
    const int e0 = i & 63;            // 8-aligned, no wrap within 8 elems
    bf16x8 o;
    o[0] = (bf16_t)__cosf(a.x + theta[e0 + 0]);
    o[1] = (bf16_t)__cosf(a.y + theta[e0 + 1]);
    o[2] = (bf16_t)__cosf(a.z + theta[e0 + 2]);
    o[3] = (bf16_t)__cosf(a.w + theta[e0 + 3]);
    o[4] = (bf16_t)__cosf(b.x + theta[e0 + 4]);
    o[5] = (bf16_t)__cosf(b.y + theta[e0 + 5]);
    o[6] = (bf16_t)__cosf(b.z + theta[e0 + 6]);
    o[7] = (bf16_t)__cosf(b.w + theta[e0 + 7]);
    *(bf16x8*)&abuf[i] = o;
}

// ---------------------------------------------------------------------------
// Stage 1: q = A @ W^T + b (M=16384, N=512, K=512), 128x128xBK64 MFMA GEMM,
// T2 both-sides swizzle (proven R4). NEW: LDS-bounce epilogue — the direct
// epilogue issued 64 scalar 2B kperm stores + 16 qt stores with lanes 8 KB
// apart (64 cache lines/instr). Now: stage D(+bias) into LDS in exact
// kperm-chunk layout -> coalesced bf16x8 global stores; second pass stages
// the [col][row] transpose for qt -> 16-thread groups write 128 contiguous
// rows per column.
// ---------------------------------------------------------------------------
__global__ __launch_bounds__(256, 2) void gemm_q_kernel(
    const bf16_t* __restrict__ abuf, const float* __restrict__ bias,
    bf16_t* __restrict__ kperm, bf16_t* __restrict__ qt)
{
    __shared__ alignas(16) bf16_t As[128 * 64];   // 16 KB
    __shared__ alignas(16) bf16_t Bs[128 * 64];   // 16 KB
    __shared__ alignas(16) bf16_t Es[128 * 136];  // 34 KB epilogue bounce

    const int t    = threadIdx.x;
    const int lane = t & 63;
    const int wave = t >> 6;
    const int l15  = lane & 15;
    const int quad = lane >> 4;
    const int m0   = (blockIdx.x >> 2) * 128;     // 128 m-tiles
    const int n0   = (blockIdx.x & 3) * 128;      // 4 n-tiles
    const int wm   = wave >> 1;                   // 0..1
    const int wn   = wave & 1;                    // 0..1

    const int drow = lane >> 3;                   // 0..7 (row within 8-row chunk)
    const int dseg = lane & 7;                    // 0..7 (16B segment)
    const int sseg = dseg ^ drow;                 // pre-swizzled source segment

    f32x4 acc[4][4];
#pragma unroll
    for (int mt = 0; mt < 4; ++mt)
#pragma unroll
        for (int nt = 0; nt < 4; ++nt) acc[mt][nt] = (f32x4){0.f, 0.f, 0.f, 0.f};

    for (int kk = 0; kk < 8; ++kk) {
        const int k0 = kk * 64;
        __syncthreads();     // previous compute done reading As/Bs
#pragma unroll
        for (int j = 0; j < 4; ++j) {
            const int c   = wave * 4 + j;         // chunk 0..15 = rows c*8..c*8+7
            const int row = c * 8 + drow;
            async_copy16(&abuf[(size_t)(m0 + row) * 512 + k0 + sseg * 8], &As[c * 512]);
            async_copy16(&Wbf_g[(size_t)(n0 + row) * 512 + k0 + sseg * 8], &Bs[c * 512]);
        }
        __syncthreads();     // DMA landed
#pragma unroll
        for (int kh = 0; kh < 2; ++kh) {
            bf16x8 af[4], bfr[4];
#pragma unroll
            for (int i = 0; i < 4; ++i) {
                const int rA = wm * 64 + i * 16 + l15;
                const int rB = wn * 64 + i * 16 + l15;
                const int sg = kh * 4 + quad;
                af[i]  = *(const bf16x8*)&As[rA * 64 + (sg ^ (rA & 7)) * 8];
                bfr[i] = *(const bf16x8*)&Bs[rB * 64 + (sg ^ (rB & 7)) * 8];
            }
#pragma unroll
            for (int mt = 0; mt < 4; ++mt)
#pragma unroll
                for (int nt = 0; nt < 4; ++nt)
                    acc[mt][nt] = __builtin_amdgcn_mfma_f32_16x16x32_bf16(af[mt], bfr[nt], acc[mt][nt], 0, 0, 0);
        }
    }

    const int b     = m0 >> 12;          // batch
    const int mloc  = m0 & 4095;         // row base within batch (mult of 128)

    // ---- pass 1: kperm via LDS bounce ----
    // chunk c = tile*8 + mh*4 + kfL (tile=rowL>>5, mh=(rowL>>4)&1, kfL=colL>>5)
    // in-chunk offset = qk*128 + (rowL&15)*8 + jj  (qk=(colL>>3)&3, jj=colL&7)
#pragma unroll
    for (int nt = 0; nt < 4; ++nt) {
        const int colL = wn * 64 + nt * 16 + l15;
        const float bv = bias[n0 + colL];
        const int kfL = colL >> 5;
        const int inc = ((colL >> 3) & 3) * 128 + (colL & 7);
#pragma unroll
        for (int mt = 0; mt < 4; ++mt) {
            const int rowL0 = wm * 64 + mt * 16 + quad * 4;
            const int c     = (rowL0 >> 5) * 8 + ((rowL0 >> 4) & 1) * 4 + kfL;
            const int base  = c * 512 + inc + (rowL0 & 15) * 8;
#pragma unroll
            for (int r = 0; r < 4; ++r)
                Es[base + r * 8] = (bf16_t)(acc[mt][nt][r] + bv);
        }
    }
    __syncthreads();
    {
        const int tileB = mloc >> 5;
        const int kfB   = n0 >> 5;
#pragma unroll
        for (int p = 0; p < 8; ++p) {
            const int flat = p * 256 + t;          // 0..2047
            const int c2   = flat >> 6;            // chunk 0..31
            const int off  = (flat & 63) * 8;
            const int tile = c2 >> 3;
            const int mh   = (c2 >> 2) & 1;
            const int kfL2 = c2 & 3;
            const size_t dst = (size_t)b * (SEQ * EMBED)
                             + (size_t)(tileB + tile) * 16384
                             + (size_t)(mh * 16 + kfB + kfL2) * 512 + off;
            *(bf16x8*)&kperm[dst] = *(const bf16x8*)&Es[c2 * 512 + off];
        }
    }
    __syncthreads();
    // ---- pass 2: qt via LDS transpose, Es as [colL][136] ----
#pragma unroll
    for (int nt = 0; nt < 4; ++nt) {
        const int colL = wn * 64 + nt * 16 + l15;
        const float bv = bias[n0 + colL];
#pragma unroll
        for (int mt = 0; mt < 4; ++mt) {
            const int rowL0 = wm * 64 + mt * 16 + quad * 4;
#pragma unroll
            for (int r = 0; r < 4; ++r)
                Es[colL * 136 + rowL0 + r] = (bf16_t)(acc[mt][nt][r] + bv);
        }
    }
    __syncthreads();
    {
#pragma unroll
        for (int p = 0; p < 8; ++p) {
            const int flat = p * 256 + t;          // 0..2047
            const int col  = flat >> 4;            // 0..127
            const int sub  = flat & 15;            // 8-row chunk
            *(bf16x8*)&qt[((size_t)(b * 512 + n0 + col) << 12) + mloc + sub * 8]
                = *(const bf16x8*)&Es[col * 136 + sub * 8];
        }
    }
}

// ---------------------------------------------------------------------------
// Stage 2: attention — R1/R4 loop with TWO isolated changes:
//  (i)  bv loads issued BEFORE the K(it+1) DMA -> PV waits vmcnt(8), DMA
//       drains at the barrier (after PV) instead of before PV.
//  (ii) setprio(1) around the PV MFMA cluster only.
// Everything else byte-identical to R4 (WRITE_SIZE=66MB is the spill check).
// ---------------------------------------------------------------------------
__global__ __launch_bounds__(256, 2) void flash_kernel(
    const bf16_t* __restrict__ kp, const bf16_t* __restrict__ qt,
    float* __restrict__ out)
{
    __shared__ alignas(16) bf16_t Ks[2][32 * 512];   // 65536 B, frag-major
    __shared__ alignas(16) bf16_t Ps[2][4 * 512];    //  8192 B, frag-major

    const int t    = threadIdx.x;
    const int lane = t & 63;
    const int wave = t >> 6;
    const int l15  = lane & 15;
    const int quad = lane >> 4;

    // XCD-aware remap: 512 blocks, xcd = L&7 owns one (batch, ksplit) group
    const int L      = blockIdx.x;            // 0..511
    const int g      = L & 7;                 // 0..7
    const int qtile  = L >> 3;                // 0..63
    const int batch  = g >> 1;
    const int ksplit = g & 1;

    const int q0     = qtile * 64;
    const int kbase  = ksplit * KT;
    const int ktile0 = kbase >> 5;            // first 32-key tile index
    const bf16_t* kpb = kp + (size_t)batch * SEQ * EMBED;
    const bf16_t* qtb = qt + (size_t)batch * EMBED * SEQ;

    // stage K-tile 0: 32 frags x 1 KB, 8 per wave, linear DMA
#pragma unroll
    for (int cc = 0; cc < 8; ++cc) {
        const int f = cc * 4 + wave;
        async_copy16(&kpb[(size_t)ktile0 * 16384 + f * 512 + lane * 8],
                     &Ks[0][f * 512]);
    }

    // Q B-frags (wave owns q-rows q0+wave*16..+15), read from frag-major kperm
    bf16x8 bQ[16];
    {
        const size_t qb = (size_t)(qtile * 2 + (wave >> 1)) * 16384
                        + (size_t)(wave & 1) * 16 * 512;
#pragma unroll
        for (int kf = 0; kf < 16; ++kf)
            bQ[kf] = *(const bf16x8*)&kpb[qb + kf * 512 + quad * 128 + l15 * 8];
    }

    f32x4 O[4][8];   // PV e-split: wave owns e-range wave*128 (8 n-tiles x 16)
#pragma unroll
    for (int m = 0; m < 4; ++m)
#pragma unroll
        for (int n = 0; n < 8; ++n) O[m][n] = (f32x4){0.f, 0.f, 0.f, 0.f};
    float lpart = 0.f;

    for (int it = 0; it < FITERS; ++it) {
        const int cbuf = it & 1;
        const int pbuf = cbuf ^ 1;
        __syncthreads();   // DMA K(it) landed; Ps(it-1) visible; Ks[pbuf] reads done
        // ---- V(it-1) global loads FIRST (older in vmcnt queue than DMA) ----
        bf16x8 bv[8];
        if (it) {
            const int kv = kbase + (it - 1) * BC;
#pragma unroll
            for (int n = 0; n < 8; ++n)
                bv[n] = *(const bf16x8*)&qtb[(size_t)(wave * 128 + n * 16 + l15) * 4096
                                             + kv + quad * 8];
        }
        // ---- issue DMA K(it+1) into Ks[pbuf] (drains at next barrier) ----
        if (it + 1 < FITERS) {
#pragma unroll
            for (int cc = 0; cc < 8; ++cc) {
                const int f = cc * 4 + wave;
                async_copy16(&kpb[(size_t)(ktile0 + it + 1) * 16384 + f * 512 + lane * 8],
                             &Ks[pbuf][f * 512]);
            }
        }
        // ---- QK(it): S^T = K * Q^T, A=K frag (seq. lane*16 read), B=Q regs ----
        f32x4 s[2];
#pragma unroll
        for (int kt = 0; kt < 2; ++kt) {
            f32x4 a = (f32x4){0.f, 0.f, 0.f, 0.f};
#pragma unroll
            for (int kf = 0; kf < 16; ++kf) {
                bf16x8 ak = *(const bf16x8*)&Ks[cbuf][(kt * 16 + kf) * 512 + lane * 8];
                a = __builtin_amdgcn_mfma_f32_16x16x32_bf16(ak, bQ[kf], a, 0, 0, 0);
            }
            s[kt] = a;
        }
        // ---- P = exp(s/8): lane holds P[q=wave*16+l15][key=kt*16+quad*4+r] ----
#pragma unroll
        for (int kt = 0; kt < 2; ++kt) {
            bf16x4 pk;
#pragma unroll
            for (int r = 0; r < 4; ++r) {
                bf16_t pb = (bf16_t)__expf(s[kt][r] * 0.125f);
                lpart += (float)pb;
                pk[r] = pb;
            }
            *(bf16x4*)&Ps[cbuf][wave * 512 + (kt * 2 + (quad >> 1)) * 128
                                + l15 * 8 + (quad & 1) * 4] = pk;
        }
        // ---- PV(it-1): A=P frags (seq. lane*16 read), B=bv ----
        if (it) {
            bf16x8 pa[4];
#pragma unroll
            for (int mt = 0; mt < 4; ++mt)
                pa[mt] = *(const bf16x8*)&Ps[pbuf][mt * 512 + lane * 8];
            __builtin_amdgcn_s_setprio(1);
#pragma unroll
            for (int n = 0; n < 8; ++n)
#pragma unroll
                for (int mt = 0; mt < 4; ++mt)
                    O[mt][n] = __builtin_amdgcn_mfma_f32_16x16x32_bf16(pa[mt], bv[n], O[mt][n], 0, 0, 0);
            __builtin_amdgcn_s_setprio(0);
        }
    }
    // ---- final PV(FITERS-1) ----
    __syncthreads();
    {
        const int pbuf = (FITERS - 1) & 1;
        const int kv = kbase + (FITERS - 1) * BC;
        bf16x8 bv[8];
#pragma unroll
        for (int n = 0; n < 8; ++n)
            bv[n] = *(const bf16x8*)&qtb[(size_t)(wave * 128 + n * 16 + l15) * 4096
                                         + kv + quad * 8];
        bf16x8 pa[4];
#pragma unroll
        for (int mt = 0; mt < 4; ++mt)
            pa[mt] = *(const bf16x8*)&Ps[pbuf][mt * 512 + lane * 8];
        __builtin_amdgcn_s_setprio(1);
#pragma unroll
        for (int n = 0; n < 8; ++n)
#pragma unroll
            for (int mt = 0; mt < 4; ++mt)
                O[mt][n] = __builtin_amdgcn_mfma_f32_16x16x32_bf16(pa[mt], bv[n], O[mt][n], 0, 0, 0);
        __builtin_amdgcn_s_setprio(0);
    }

    // ---- row exp-sums: row = wave*16+l15, keys spread over quad ----
    {
        float ls = lpart;
        ls += __shfl_xor(ls, 16);
        ls += __shfl_xor(ls, 32);
        if (quad == 0)
            atomicAdd(&Lacc_g[batch * SEQ + q0 + wave * 16 + l15], ls);
    }
    // ---- unnormalized O -> out; D: row=quad*4+r (q-row), col=l15 (e) ----
#pragma unroll
    for (int mt = 0; mt < 4; ++mt)
#pragma unroll
        for (int r = 0; r < 4; ++r) {
            const size_t row = (size_t)batch * SEQ + q0 + mt * 16 + quad * 4 + r;
#pragma unroll
            for (int n = 0; n < 8; ++n)
                atomicAdd(&out[row * 512 + wave * 128 + n * 16 + l15], O[mt][n][r]);
        }
}

// out[row][e] /= Lacc_g[row]
__global__ __launch_bounds__(256) void norm_kernel(float* __restrict__ out)
{
    const int idx = blockIdx.x * 256 + threadIdx.x;   // float4 index
    float4 v = ((float4*)out)[idx];
    const float inv = 1.0f / Lacc_g[idx >> 7];
    v.x *= inv; v.y *= inv; v.z *= inv; v.w *= inv;
    ((float4*)out)[idx] = v;
}

extern "C" void kernel_launch(void* const* d_in, const int* in_sizes, int n_in,
                              void* d_out, int out_size, void* d_ws, size_t ws_size,
                              hipStream_t stream) {
    const float* x     = (const float*)d_in[0];
    const float* theta = (const float*)d_in[1];
    const float* W     = (const float*)d_in[2];
    const float* bias  = (const float*)d_in[3];
    float* out    = (float*)d_out;
    bf16_t* kperm = (bf16_t*)d_ws;                      // [4][128 tiles][32 frags][512] bf16
    bf16_t* qt    = kperm + (size_t)MTOT * EMBED;       // [4][512][4096] bf16
    bf16_t* abuf  = qt + (size_t)MTOT * EMBED;          // [16384][512] bf16

    hipMemsetAsync(out, 0, (size_t)MTOT * EMBED * sizeof(float), stream);

    cvt_w_kernel<<<dim3(EMBED * EMBED / 4 / 256), dim3(256), 0, stream>>>(W);

    cvt_a_kernel<<<dim3(MTOT * EMBED / 8 / 256), dim3(256), 0, stream>>>(x, theta, abuf);

    gemm_q_kernel<<<dim3((MTOT / 128) * 4), dim3(256), 0, stream>>>(abuf, bias, kperm, qt);

    flash_kernel<<<dim3(64 * BATCH * NSPLIT), dim3(256), 0, stream>>>(kperm, qt, out);

    norm_kernel<<<dim3(MTOT * EMBED / 4 / 256), dim3(256), 0, stream>>>(out);
}

// Round 6
// 340.937 us; speedup vs baseline: 1.4060x; 1.0739x over previous
//
#include <hip/hip_runtime.h>

typedef __bf16 bf16_t;
typedef bf16_t bf16x8 __attribute__((ext_vector_type(8)));
typedef bf16_t bf16x4 __attribute__((ext_vector_type(4)));
typedef float f32x4 __attribute__((ext_vector_type(4)));

#define BATCH 4
#define SEQ 4096
#define EMBED 512
#define MTOT (BATCH * SEQ)
#define NSPLIT 2
#define KT (SEQ / NSPLIT)     // 2048 keys per block
#define BC 32
#define FITERS (KT / BC)      // 64

__device__ float  Lbuf_g[NSPLIT][MTOT];  // per-ksplit row exp-sums (plain stores)
__device__ bf16_t Wbf_g[EMBED * EMBED];  // W pre-converted to bf16

// async global->LDS, 16 B per lane; lds base must be wave-uniform
__device__ __forceinline__ void async_copy16(const bf16_t* g, bf16_t* l) {
    __builtin_amdgcn_global_load_lds(
        (const __attribute__((address_space(1))) unsigned int*)g,
        (__attribute__((address_space(3))) unsigned int*)l, 16, 0, 0);
}

// ---------------------------------------------------------------------------
// Stage 0a: W fp32 -> bf16 once.
// ---------------------------------------------------------------------------
__global__ __launch_bounds__(256) void cvt_w_kernel(const float* __restrict__ W) {
    const int i = (blockIdx.x * 256 + threadIdx.x) * 4;
    float4 v = *(const float4*)&W[i];
    bf16x4 o;
    o[0] = (bf16_t)v.x; o[1] = (bf16_t)v.y; o[2] = (bf16_t)v.z; o[3] = (bf16_t)v.w;
    *(bf16x4*)&Wbf_g[i] = o;
}

// ---------------------------------------------------------------------------
// Stage 0b: abuf = bf16(cos(x + theta)) — A operand precomputed once.
// ---------------------------------------------------------------------------
__global__ __launch_bounds__(256) void cvt_a_kernel(
    const float* __restrict__ x, const float* __restrict__ theta,
    bf16_t* __restrict__ abuf)
{
    const int i = (blockIdx.x * 256 + threadIdx.x) * 8;
    float4 a = *(const float4*)&x[i];
    float4 b = *(const float4*)&x[i + 4];
    const int e0 = i & 63;            // 8-aligned, no wrap within 8 elems
    bf16x8 o;
    o[0] = (bf16_t)__cosf(a.x + theta[e0 + 0]);
    o[1] = (bf16_t)__cosf(a.y + theta[e0 + 1]);
    o[2] = (bf16_t)__cosf(a.z + theta[e0 + 2]);
    o[3] = (bf16_t)__cosf(a.w + theta[e0 + 3]);
    o[4] = (bf16_t)__cosf(b.x + theta[e0 + 4]);
    o[5] = (bf16_t)__cosf(b.y + theta[e0 + 5]);
    o[6] = (bf16_t)__cosf(b.z + theta[e0 + 6]);
    o[7] = (bf16_t)__cosf(b.w + theta[e0 + 7]);
    *(bf16x8*)&abuf[i] = o;
}

// ---------------------------------------------------------------------------
// Stage 1: q = A @ W^T + b (M=16384, N=512, K=512), 128x128xBK64 MFMA GEMM,
// T2 both-sides swizzle + LDS-bounce epilogue (unchanged from R5).
// ---------------------------------------------------------------------------
__global__ __launch_bounds__(256, 2) void gemm_q_kernel(
    const bf16_t* __restrict__ abuf, const float* __restrict__ bias,
    bf16_t* __restrict__ kperm, bf16_t* __restrict__ qt)
{
    __shared__ alignas(16) bf16_t As[128 * 64];   // 16 KB
    __shared__ alignas(16) bf16_t Bs[128 * 64];   // 16 KB
    __shared__ alignas(16) bf16_t Es[128 * 136];  // 34 KB epilogue bounce

    const int t    = threadIdx.x;
    const int lane = t & 63;
    const int wave = t >> 6;
    const int l15  = lane & 15;
    const int quad = lane >> 4;
    const int m0   = (blockIdx.x >> 2) * 128;     // 128 m-tiles
    const int n0   = (blockIdx.x & 3) * 128;      // 4 n-tiles
    const int wm   = wave >> 1;                   // 0..1
    const int wn   = wave & 1;                    // 0..1

    const int drow = lane >> 3;                   // 0..7 (row within 8-row chunk)
    const int dseg = lane & 7;                    // 0..7 (16B segment)
    const int sseg = dseg ^ drow;                 // pre-swizzled source segment

    f32x4 acc[4][4];
#pragma unroll
    for (int mt = 0; mt < 4; ++mt)
#pragma unroll
        for (int nt = 0; nt < 4; ++nt) acc[mt][nt] = (f32x4){0.f, 0.f, 0.f, 0.f};

    for (int kk = 0; kk < 8; ++kk) {
        const int k0 = kk * 64;
        __syncthreads();     // previous compute done reading As/Bs
#pragma unroll
        for (int j = 0; j < 4; ++j) {
            const int c   = wave * 4 + j;         // chunk 0..15 = rows c*8..c*8+7
            const int row = c * 8 + drow;
            async_copy16(&abuf[(size_t)(m0 + row) * 512 + k0 + sseg * 8], &As[c * 512]);
            async_copy16(&Wbf_g[(size_t)(n0 + row) * 512 + k0 + sseg * 8], &Bs[c * 512]);
        }
        __syncthreads();     // DMA landed
#pragma unroll
        for (int kh = 0; kh < 2; ++kh) {
            bf16x8 af[4], bfr[4];
#pragma unroll
            for (int i = 0; i < 4; ++i) {
                const int rA = wm * 64 + i * 16 + l15;
                const int rB = wn * 64 + i * 16 + l15;
                const int sg = kh * 4 + quad;
                af[i]  = *(const bf16x8*)&As[rA * 64 + (sg ^ (rA & 7)) * 8];
                bfr[i] = *(const bf16x8*)&Bs[rB * 64 + (sg ^ (rB & 7)) * 8];
            }
#pragma unroll
            for (int mt = 0; mt < 4; ++mt)
#pragma unroll
                for (int nt = 0; nt < 4; ++nt)
                    acc[mt][nt] = __builtin_amdgcn_mfma_f32_16x16x32_bf16(af[mt], bfr[nt], acc[mt][nt], 0, 0, 0);
        }
    }

    const int b     = m0 >> 12;          // batch
    const int mloc  = m0 & 4095;         // row base within batch (mult of 128)

    // ---- pass 1: kperm via LDS bounce ----
#pragma unroll
    for (int nt = 0; nt < 4; ++nt) {
        const int colL = wn * 64 + nt * 16 + l15;
        const float bv = bias[n0 + colL];
        const int kfL = colL >> 5;
        const int inc = ((colL >> 3) & 3) * 128 + (colL & 7);
#pragma unroll
        for (int mt = 0; mt < 4; ++mt) {
            const int rowL0 = wm * 64 + mt * 16 + quad * 4;
            const int c     = (rowL0 >> 5) * 8 + ((rowL0 >> 4) & 1) * 4 + kfL;
            const int base  = c * 512 + inc + (rowL0 & 15) * 8;
#pragma unroll
            for (int r = 0; r < 4; ++r)
                Es[base + r * 8] = (bf16_t)(acc[mt][nt][r] + bv);
        }
    }
    __syncthreads();
    {
        const int tileB = mloc >> 5;
        const int kfB   = n0 >> 5;
#pragma unroll
        for (int p = 0; p < 8; ++p) {
            const int flat = p * 256 + t;          // 0..2047
            const int c2   = flat >> 6;            // chunk 0..31
            const int off  = (flat & 63) * 8;
            const int tile = c2 >> 3;
            const int mh   = (c2 >> 2) & 1;
            const int kfL2 = c2 & 3;
            const size_t dst = (size_t)b * (SEQ * EMBED)
                             + (size_t)(tileB + tile) * 16384
                             + (size_t)(mh * 16 + kfB + kfL2) * 512 + off;
            *(bf16x8*)&kperm[dst] = *(const bf16x8*)&Es[c2 * 512 + off];
        }
    }
    __syncthreads();
    // ---- pass 2: qt via LDS transpose, Es as [colL][136] ----
#pragma unroll
    for (int nt = 0; nt < 4; ++nt) {
        const int colL = wn * 64 + nt * 16 + l15;
        const float bv = bias[n0 + colL];
#pragma unroll
        for (int mt = 0; mt < 4; ++mt) {
            const int rowL0 = wm * 64 + mt * 16 + quad * 4;
#pragma unroll
            for (int r = 0; r < 4; ++r)
                Es[colL * 136 + rowL0 + r] = (bf16_t)(acc[mt][nt][r] + bv);
        }
    }
    __syncthreads();
    {
#pragma unroll
        for (int p = 0; p < 8; ++p) {
            const int flat = p * 256 + t;          // 0..2047
            const int col  = flat >> 4;            // 0..127
            const int sub  = flat & 15;            // 8-row chunk
            *(bf16x8*)&qt[((size_t)(b * 512 + n0 + col) << 12) + mloc + sub * 8]
                = *(const bf16x8*)&Es[col * 136 + sub * 8];
        }
    }
}

// ---------------------------------------------------------------------------
// Stage 2: attention — loop byte-identical to R5 (268 us proven). ONLY the
// epilogue changes: per-ksplit partial O -> non-temporal plain stores into
// obuf (summed+normalized in norm_kernel), replacing 16.8M contended float
// atomicAdds. Row exp-sums go to Lbuf_g[ksplit][row] via plain stores
// (unique writer). Runtime fallback to the atomic path if ws is too small.
// ---------------------------------------------------------------------------
__global__ __launch_bounds__(256, 2) void flash_kernel(
    const bf16_t* __restrict__ kp, const bf16_t* __restrict__ qt,
    float* __restrict__ out, float* __restrict__ obuf, const int split)
{
    __shared__ alignas(16) bf16_t Ks[2][32 * 512];   // 65536 B, frag-major
    __shared__ alignas(16) bf16_t Ps[2][4 * 512];    //  8192 B, frag-major

    const int t    = threadIdx.x;
    const int lane = t & 63;
    const int wave = t >> 6;
    const int l15  = lane & 15;
    const int quad = lane >> 4;

    // XCD-aware remap: 512 blocks, xcd = L&7 owns one (batch, ksplit) group
    const int L      = blockIdx.x;            // 0..511
    const int g      = L & 7;                 // 0..7
    const int qtile  = L >> 3;                // 0..63
    const int batch  = g >> 1;
    const int ksplit = g & 1;

    const int q0     = qtile * 64;
    const int kbase  = ksplit * KT;
    const int ktile0 = kbase >> 5;            // first 32-key tile index
    const bf16_t* kpb = kp + (size_t)batch * SEQ * EMBED;
    const bf16_t* qtb = qt + (size_t)batch * EMBED * SEQ;

    // stage K-tile 0: 32 frags x 1 KB, 8 per wave, linear DMA
#pragma unroll
    for (int cc = 0; cc < 8; ++cc) {
        const int f = cc * 4 + wave;
        async_copy16(&kpb[(size_t)ktile0 * 16384 + f * 512 + lane * 8],
                     &Ks[0][f * 512]);
    }

    // Q B-frags (wave owns q-rows q0+wave*16..+15), read from frag-major kperm
    bf16x8 bQ[16];
    {
        const size_t qb = (size_t)(qtile * 2 + (wave >> 1)) * 16384
                        + (size_t)(wave & 1) * 16 * 512;
#pragma unroll
        for (int kf = 0; kf < 16; ++kf)
            bQ[kf] = *(const bf16x8*)&kpb[qb + kf * 512 + quad * 128 + l15 * 8];
    }

    f32x4 O[4][8];   // PV e-split: wave owns e-range wave*128 (8 n-tiles x 16)
#pragma unroll
    for (int m = 0; m < 4; ++m)
#pragma unroll
        for (int n = 0; n < 8; ++n) O[m][n] = (f32x4){0.f, 0.f, 0.f, 0.f};
    float lpart = 0.f;

    for (int it = 0; it < FITERS; ++it) {
        const int cbuf = it & 1;
        const int pbuf = cbuf ^ 1;
        __syncthreads();   // DMA K(it) landed; Ps(it-1) visible; Ks[pbuf] reads done
        // ---- V(it-1) global loads FIRST (older in vmcnt queue than DMA) ----
        bf16x8 bv[8];
        if (it) {
            const int kv = kbase + (it - 1) * BC;
#pragma unroll
            for (int n = 0; n < 8; ++n)
                bv[n] = *(const bf16x8*)&qtb[(size_t)(wave * 128 + n * 16 + l15) * 4096
                                             + kv + quad * 8];
        }
        // ---- issue DMA K(it+1) into Ks[pbuf] (drains at next barrier) ----
        if (it + 1 < FITERS) {
#pragma unroll
            for (int cc = 0; cc < 8; ++cc) {
                const int f = cc * 4 + wave;
                async_copy16(&kpb[(size_t)(ktile0 + it + 1) * 16384 + f * 512 + lane * 8],
                             &Ks[pbuf][f * 512]);
            }
        }
        // ---- QK(it): S^T = K * Q^T, A=K frag (seq. lane*16 read), B=Q regs ----
        f32x4 s[2];
#pragma unroll
        for (int kt = 0; kt < 2; ++kt) {
            f32x4 a = (f32x4){0.f, 0.f, 0.f, 0.f};
#pragma unroll
            for (int kf = 0; kf < 16; ++kf) {
                bf16x8 ak = *(const bf16x8*)&Ks[cbuf][(kt * 16 + kf) * 512 + lane * 8];
                a = __builtin_amdgcn_mfma_f32_16x16x32_bf16(ak, bQ[kf], a, 0, 0, 0);
            }
            s[kt] = a;
        }
        // ---- P = exp(s/8): lane holds P[q=wave*16+l15][key=kt*16+quad*4+r] ----
#pragma unroll
        for (int kt = 0; kt < 2; ++kt) {
            bf16x4 pk;
#pragma unroll
            for (int r = 0; r < 4; ++r) {
                bf16_t pb = (bf16_t)__expf(s[kt][r] * 0.125f);
                lpart += (float)pb;
                pk[r] = pb;
            }
            *(bf16x4*)&Ps[cbuf][wave * 512 + (kt * 2 + (quad >> 1)) * 128
                                + l15 * 8 + (quad & 1) * 4] = pk;
        }
        // ---- PV(it-1): A=P frags (seq. lane*16 read), B=bv ----
        if (it) {
            bf16x8 pa[4];
#pragma unroll
            for (int mt = 0; mt < 4; ++mt)
                pa[mt] = *(const bf16x8*)&Ps[pbuf][mt * 512 + lane * 8];
            __builtin_amdgcn_s_setprio(1);
#pragma unroll
            for (int n = 0; n < 8; ++n)
#pragma unroll
                for (int mt = 0; mt < 4; ++mt)
                    O[mt][n] = __builtin_amdgcn_mfma_f32_16x16x32_bf16(pa[mt], bv[n], O[mt][n], 0, 0, 0);
            __builtin_amdgcn_s_setprio(0);
        }
    }
    // ---- final PV(FITERS-1) ----
    __syncthreads();
    {
        const int pbuf = (FITERS - 1) & 1;
        const int kv = kbase + (FITERS - 1) * BC;
        bf16x8 bv[8];
#pragma unroll
        for (int n = 0; n < 8; ++n)
            bv[n] = *(const bf16x8*)&qtb[(size_t)(wave * 128 + n * 16 + l15) * 4096
                                         + kv + quad * 8];
        bf16x8 pa[4];
#pragma unroll
        for (int mt = 0; mt < 4; ++mt)
            pa[mt] = *(const bf16x8*)&Ps[pbuf][mt * 512 + lane * 8];
        __builtin_amdgcn_s_setprio(1);
#pragma unroll
        for (int n = 0; n < 8; ++n)
#pragma unroll
            for (int mt = 0; mt < 4; ++mt)
                O[mt][n] = __builtin_amdgcn_mfma_f32_16x16x32_bf16(pa[mt], bv[n], O[mt][n], 0, 0, 0);
        __builtin_amdgcn_s_setprio(0);
    }

    // ---- row exp-sums: plain store, unique writer per (row, ksplit) ----
    {
        float ls = lpart;
        ls += __shfl_xor(ls, 16);
        ls += __shfl_xor(ls, 32);
        if (quad == 0)
            Lbuf_g[ksplit][batch * SEQ + q0 + wave * 16 + l15] = ls;
    }
    // ---- unnormalized O; D: row=quad*4+r (q-row), col=l15 (e) ----
    if (split) {
        float* ob = obuf + (size_t)ksplit * MTOT * EMBED;
#pragma unroll
        for (int mt = 0; mt < 4; ++mt)
#pragma unroll
            for (int r = 0; r < 4; ++r) {
                const size_t row = (size_t)batch * SEQ + q0 + mt * 16 + quad * 4 + r;
#pragma unroll
                for (int n = 0; n < 8; ++n)
                    __builtin_nontemporal_store(O[mt][n][r],
                        &ob[row * 512 + wave * 128 + n * 16 + l15]);
            }
    } else {
#pragma unroll
        for (int mt = 0; mt < 4; ++mt)
#pragma unroll
            for (int r = 0; r < 4; ++r) {
                const size_t row = (size_t)batch * SEQ + q0 + mt * 16 + quad * 4 + r;
#pragma unroll
                for (int n = 0; n < 8; ++n)
                    atomicAdd(&out[row * 512 + wave * 128 + n * 16 + l15], O[mt][n][r]);
            }
    }
}

// out[row][e] = (split ? obuf0+obuf1 : out)[row][e] / (Lbuf[0][row]+Lbuf[1][row])
__global__ __launch_bounds__(256) void norm_kernel(
    float* __restrict__ out, const float* __restrict__ obuf, const int split)
{
    const int idx = blockIdx.x * 256 + threadIdx.x;   // float4 index
    const int row = idx >> 7;
    float4 v;
    if (split) {
        float4 a = ((const float4*)obuf)[idx];
        float4 b = ((const float4*)(obuf + (size_t)MTOT * EMBED))[idx];
        v = make_float4(a.x + b.x, a.y + b.y, a.z + b.z, a.w + b.w);
    } else {
        v = ((float4*)out)[idx];
    }
    const float inv = 1.0f / (Lbuf_g[0][row] + Lbuf_g[1][row]);
    v.x *= inv; v.y *= inv; v.z *= inv; v.w *= inv;
    ((float4*)out)[idx] = v;
}

extern "C" void kernel_launch(void* const* d_in, const int* in_sizes, int n_in,
                              void* d_out, int out_size, void* d_ws, size_t ws_size,
                              hipStream_t stream) {
    const float* x     = (const float*)d_in[0];
    const float* theta = (const float*)d_in[1];
    const float* W     = (const float*)d_in[2];
    const float* bias  = (const float*)d_in[3];
    float* out    = (float*)d_out;
    bf16_t* kperm = (bf16_t*)d_ws;                      // [4][128 tiles][32 frags][512] bf16
    bf16_t* qt    = kperm + (size_t)MTOT * EMBED;       // [4][512][4096] bf16
    bf16_t* abuf  = qt + (size_t)MTOT * EMBED;          // [16384][512] bf16
    float*  obuf  = (float*)(abuf + (size_t)MTOT * EMBED); // [2][16384][512] f32 (optional)

    const size_t need = (size_t)MTOT * EMBED * (2 + 2 + 2 + 8); // 3 bf16 bufs + 2 f32 partials
    const int split = (ws_size >= need) ? 1 : 0;

    if (!split)
        hipMemsetAsync(out, 0, (size_t)MTOT * EMBED * sizeof(float), stream);

    cvt_w_kernel<<<dim3(EMBED * EMBED / 4 / 256), dim3(256), 0, stream>>>(W);

    cvt_a_kernel<<<dim3(MTOT * EMBED / 8 / 256), dim3(256), 0, stream>>>(x, theta, abuf);

    gemm_q_kernel<<<dim3((MTOT / 128) * 4), dim3(256), 0, stream>>>(abuf, bias, kperm, qt);

    flash_kernel<<<dim3(64 * BATCH * NSPLIT), dim3(256), 0, stream>>>(kperm, qt, out, obuf, split);

    norm_kernel<<<dim3(MTOT * EMBED / 4 / 256), dim3(256), 0, stream>>>(out, obuf, split);
}